// Round 7
// baseline (267.454 us; speedup 1.0000x reference)
//
#include <hip/hip_runtime.h>

// LengthRegulator: expand x[B,L,D] along L per integer durations into out[B,T,D].
// B=64, L=256, D=512, T=max_length=1792. Out: (out [B,T,D] f32, max_length).
//
// v6: two-kernel split. Round-6 result: plain stores + batch-4 took the
// kernel 74 -> ~68us (dur 269.8 -> 263.7); remaining gap to the ~40us write
// roofline attributed to every one of 1792 blocks redoing the 256-wide
// LDS scan (16 barriers) before storing anything (28x duplication per b).
//   kernel 1 (64 blocks):  scan once per b, scatter idx[B][T] into d_ws
//   kernel 2 (1792 blocks): pure copy stream — no LDS, no barriers;
//                           wave-uniform idx load, batch-4 gather/store,
//                           XCD-locality swizzle retained, plain stores.

#define BB 64
#define LL 256
#define DD 512
#define TT 1792
#define D4 (DD / 4)          // 128 float4 per row
#define TILE 64              // frames per block; TT = 28 * TILE exact
#define NBT (TT / TILE)      // 28 t-blocks per b
#define NBLK (BB * NBT)      // 1792 blocks

typedef float f32x4 __attribute__((ext_vector_type(4)));

// ---------- kernel 1: per-b scan + scatter idx table ----------
__global__ __launch_bounds__(256) void scan_scatter_kernel(
    const int* __restrict__ dur,     // [B, L]
    const int* __restrict__ maxlen,  // [1]
    int*       __restrict__ idx_g,   // [B, T] in d_ws
    float*     __restrict__ out)     // for the max_length scalar
{
    __shared__ int cum[LL];
    const int tid = threadIdx.x;
    const int b   = blockIdx.x;

    // inclusive scan of durations (ALPHA = 1.0 -> round(d*1.0) == d)
    cum[tid] = dur[b * LL + tid];
    __syncthreads();
    #pragma unroll
    for (int off = 1; off < LL; off <<= 1) {
        int v = (tid >= off) ? cum[tid - off] : 0;
        __syncthreads();
        cum[tid] += v;
        __syncthreads();
    }
    // all-zero row: d[0] = 1 -> cum[j] = 1 for all j
    if (cum[LL - 1] == 0) cum[tid] = 1;
    __syncthreads();

    // init idx to -1 (zero frame), then scatter phoneme index over
    // [cum[j-1], cum[j])  — reproduces searchsorted(cum, t, 'right').
    int* idxb = idx_g + b * TT;
    #pragma unroll
    for (int t = tid; t < TT; t += 256) idxb[t] = -1;
    __syncthreads();
    {
        const int end   = cum[tid];                    // <= 1792 = T
        const int start = (tid > 0) ? cum[tid - 1] : 0;
        for (int t = start; t < end; ++t) idxb[t] = tid;
    }

    // output 1: max_length as float
    if (b == 0 && tid == 0) out[(size_t)BB * TT * DD] = (float)maxlen[0];
}

// ---------- kernel 2: pure copy stream ----------
__global__ __launch_bounds__(256) void copy_kernel(
    const f32x4* __restrict__ x4,     // [B, L, D4]
    const int*   __restrict__ idx_g,  // [B, T]
    float*       __restrict__ out)    // [B*T*D + 1]
{
    // XCD-locality swizzle: XCD k owns b in [8k, 8k+8) -> 4MB x-panel per L2.
    const int bid  = blockIdx.x;
    const int virt = (bid & 7) * (NBLK / 8) + (bid >> 3);
    const int b    = virt / NBT;
    const int t0   = (virt % NBT) * TILE;

    const int tid   = threadIdx.x;
    const int group = tid >> 7;   // 0..1
    const int lane  = tid & 127;  // float4 index within row
    const f32x4 z   = (f32x4)(0.f);
    const f32x4* __restrict__ xrow = x4 + (size_t)b * LL * D4;
    const int*   __restrict__ idxb = idx_g + b * TT + t0;
    f32x4* __restrict__ outb = (f32x4*)out + ((size_t)b * TT + t0) * D4;

    #pragma unroll
    for (int itb = 0; itb < TILE / 2; itb += 4) {
        const int ta = (itb + 0) * 2 + group;
        const int tb = (itb + 1) * 2 + group;
        const int tc = (itb + 2) * 2 + group;
        const int td = (itb + 3) * 2 + group;
        const int ia = idxb[ta];   // wave-uniform -> L1 broadcast
        const int ib = idxb[tb];
        const int ic = idxb[tc];
        const int ie = idxb[td];
        f32x4 va = xrow[max(ia, 0) * D4 + lane];
        f32x4 vb = xrow[max(ib, 0) * D4 + lane];
        f32x4 vc = xrow[max(ic, 0) * D4 + lane];
        f32x4 ve = xrow[max(ie, 0) * D4 + lane];
        va = (ia >= 0) ? va : z;
        vb = (ib >= 0) ? vb : z;
        vc = (ic >= 0) ? vc : z;
        ve = (ie >= 0) ? ve : z;
        outb[ta * D4 + lane] = va;
        outb[tb * D4 + lane] = vb;
        outb[tc * D4 + lane] = vc;
        outb[td * D4 + lane] = ve;
    }
}

// ---------- fallback single-kernel (if workspace too small) ----------
__global__ __launch_bounds__(256) void length_regulator_fused(
    const f32x4* __restrict__ x4, const int* __restrict__ dur,
    const int* __restrict__ maxlen, float* __restrict__ out)
{
    __shared__ int cum[LL];
    __shared__ int idx_s[TILE];
    const int tid = threadIdx.x;
    const int bid  = blockIdx.x;
    const int virt = (bid & 7) * (NBLK / 8) + (bid >> 3);
    const int b    = virt / NBT;
    const int t0   = (virt % NBT) * TILE;

    cum[tid] = dur[b * LL + tid];
    if (tid < TILE) idx_s[tid] = -1;
    __syncthreads();
    #pragma unroll
    for (int off = 1; off < LL; off <<= 1) {
        int v = (tid >= off) ? cum[tid - off] : 0;
        __syncthreads();
        cum[tid] += v;
        __syncthreads();
    }
    if (cum[LL - 1] == 0) cum[tid] = 1;
    __syncthreads();
    {
        const int end   = cum[tid];
        const int start = (tid > 0) ? cum[tid - 1] : 0;
        const int lo = max(start, t0);
        const int hi = min(end, t0 + TILE);
        for (int t = lo; t < hi; ++t) idx_s[t - t0] = tid;
    }
    __syncthreads();

    const int group = tid >> 7;
    const int lane  = tid & 127;
    const f32x4 z   = (f32x4)(0.f);
    const f32x4* __restrict__ xrow = x4 + (size_t)b * LL * D4;
    f32x4* __restrict__ outb = (f32x4*)out + ((size_t)b * TT + t0) * D4;

    #pragma unroll
    for (int itb = 0; itb < TILE / 2; itb += 4) {
        const int ta = (itb + 0) * 2 + group;
        const int tb = (itb + 1) * 2 + group;
        const int tc = (itb + 2) * 2 + group;
        const int td = (itb + 3) * 2 + group;
        const int ia = idx_s[ta];
        const int ib = idx_s[tb];
        const int ic = idx_s[tc];
        const int ie = idx_s[td];
        f32x4 va = xrow[max(ia, 0) * D4 + lane];
        f32x4 vb = xrow[max(ib, 0) * D4 + lane];
        f32x4 vc = xrow[max(ic, 0) * D4 + lane];
        f32x4 ve = xrow[max(ie, 0) * D4 + lane];
        va = (ia >= 0) ? va : z;
        vb = (ib >= 0) ? vb : z;
        vc = (ic >= 0) ? vc : z;
        ve = (ie >= 0) ? ve : z;
        outb[ta * D4 + lane] = va;
        outb[tb * D4 + lane] = vb;
        outb[tc * D4 + lane] = vc;
        outb[td * D4 + lane] = ve;
    }
    if (virt == 0 && tid == 0) out[(size_t)BB * TT * DD] = (float)maxlen[0];
}

extern "C" void kernel_launch(void* const* d_in, const int* in_sizes, int n_in,
                              void* d_out, int out_size, void* d_ws, size_t ws_size,
                              hipStream_t stream) {
    const f32x4* x4  = (const f32x4*)d_in[0];
    const int*   dur = (const int*)d_in[1];
    const int*   ml  = (const int*)d_in[2];
    float*       out = (float*)d_out;

    const size_t idx_bytes = (size_t)BB * TT * sizeof(int);  // 458752 B
    if (d_ws != nullptr && ws_size >= idx_bytes) {
        int* idx_g = (int*)d_ws;
        scan_scatter_kernel<<<dim3(BB), dim3(256), 0, stream>>>(dur, ml, idx_g, out);
        copy_kernel<<<dim3(NBLK), dim3(256), 0, stream>>>(x4, idx_g, out);
    } else {
        length_regulator_fused<<<dim3(NBLK), dim3(256), 0, stream>>>(x4, dur, ml, out);
    }
}

// Round 8
// 265.959 us; speedup vs baseline: 1.0056x; 1.0056x over previous
//
#include <hip/hip_runtime.h>

// LengthRegulator: expand x[B,L,D] along L per integer durations into out[B,T,D].
// B=64, L=256, D=512, T=max_length=1792. Out: (out [B,T,D] f32, max_length).
//
// v7 (fused; v6 split regressed +4us): attack fabric READ traffic + scan cost.
//  - run-dedupe gather: idx non-decreasing; each group owns 32 CONTIGUOUS
//    frames and reloads x only when id changes (wave-uniform branch).
//    ~3.2x fewer row loads (~117MB -> ~37MB fabric reads); zero-tail frames
//    load nothing at all (v5 clamped-load wasted a row-0 load per zero frame).
//  - shuffle scan: wave __shfl_up inclusive scan + 4-wave combine; 2 barriers
//    instead of 16; no cum[] LDS (scatter uses each thread's own (c-d, c)).
//  - plain stores (NT measured 4.16 vs 6.4 TB/s), batchy unrolled store loop,
//    XCD-locality swizzle (XCD k owns b in [8k,8k+8) -> 4MB x-panel per L2).

#define BB 64
#define LL 256
#define DD 512
#define TT 1792
#define D4 (DD / 4)          // 128 float4 per row
#define TILE 64              // frames per block; TT = 28 * TILE exact
#define NBT (TT / TILE)      // 28 t-blocks per b
#define NBLK (BB * NBT)      // 1792 blocks

typedef float f32x4 __attribute__((ext_vector_type(4)));

__global__ __launch_bounds__(256) void length_regulator_kernel(
    const f32x4* __restrict__ x4,       // [B, L, D4]
    const int*   __restrict__ dur,      // [B, L]
    const int*   __restrict__ maxlen,   // [1]
    float*       __restrict__ out)      // [B*T*D + 1]
{
    __shared__ int wsum[4];
    __shared__ int idx_s[TILE];
    const int tid = threadIdx.x;

    // XCD-locality swizzle: XCD k owns b in [8k, 8k+8).
    const int bid  = blockIdx.x;
    const int virt = (bid & 7) * (NBLK / 8) + (bid >> 3);
    const int b    = virt / NBT;
    const int t0   = (virt % NBT) * TILE;

    // --- inclusive scan of durations: wave shuffle scan + 4-wave combine ---
    // ALPHA = 1.0 -> round(d * 1.0) == d
    int d = dur[b * LL + tid];
    int c = d;
    #pragma unroll
    for (int off = 1; off < 64; off <<= 1) {
        int u = __shfl_up(c, off, 64);
        if ((tid & 63) >= off) c += u;
    }
    if (tid < TILE) idx_s[tid] = -1;          // -1 = "zero frame"
    if ((tid & 63) == 63) wsum[tid >> 6] = c; // wave totals
    __syncthreads();
    {
        const int s0 = wsum[0], s1 = wsum[1], s2 = wsum[2], s3 = wsum[3];
        const int wid   = tid >> 6;
        const int total = s0 + s1 + s2 + s3;
        c += (wid > 0 ? s0 : 0) + (wid > 1 ? s1 : 0) + (wid > 2 ? s2 : 0);
        // all-zero row: d[0] = 1 -> cum[j] = 1 for all j
        if (total == 0) { c = 1; d = (tid == 0) ? 1 : 0; }
    }

    // --- scatter: thread j stamps idx over [c-d, c) ∩ [t0, t0+TILE) ---
    // Reproduces searchsorted(cum, t, 'right'). <= 7 LDS writes/thread.
    {
        const int lo = max(c - d, t0);
        const int hi = min(c, t0 + TILE);
        for (int t = lo; t < hi; ++t) idx_s[t - t0] = tid;
    }
    __syncthreads();

    // --- copy: 2 groups x 128 lanes; group g owns frames [32g, 32g+32) ---
    // idx is non-decreasing: reload x only when id changes (wave-uniform
    // branch; avg run length ~3.5 -> ~3x fewer row loads; zero tail loads 0).
    const int group = tid >> 7;   // 0..1
    const int lane  = tid & 127;  // float4 index within row
    const f32x4 z   = (f32x4)(0.f);
    const f32x4* __restrict__ xrow = x4 + (size_t)b * LL * D4;
    f32x4* __restrict__ outb = (f32x4*)out + ((size_t)b * TT + t0) * D4;

    int   prev = -2;              // sentinel != any id and != -1
    f32x4 v    = z;
    #pragma unroll
    for (int it = 0; it < TILE / 2; ++it) {
        const int toff = (group << 5) + it;   // contiguous 32-frame half
        const int id   = idx_s[toff];         // uniform per wave
        if (id != prev) {                     // wave-uniform branch
            v = (id >= 0) ? xrow[id * D4 + lane] : z;
            prev = id;
        }
        outb[toff * D4 + lane] = v;
    }

    // --- output 1: max_length as float, one thread writes it ---
    if (virt == 0 && tid == 0) {
        out[(size_t)BB * TT * DD] = (float)maxlen[0];
    }
}

extern "C" void kernel_launch(void* const* d_in, const int* in_sizes, int n_in,
                              void* d_out, int out_size, void* d_ws, size_t ws_size,
                              hipStream_t stream) {
    const f32x4* x4  = (const f32x4*)d_in[0];
    const int*   dur = (const int*)d_in[1];
    const int*   ml  = (const int*)d_in[2];
    float*       out = (float*)d_out;

    length_regulator_kernel<<<dim3(NBLK), dim3(256), 0, stream>>>(x4, dur, ml, out);
}